// Round 1
// baseline (126.581 us; speedup 1.0000x reference)
//
#include <hip/hip_runtime.h>
#include <hip/hip_bf16.h>

typedef __bf16 bhalf;
typedef bhalf bhalf8 __attribute__((ext_vector_type(8)));
typedef float f32x4 __attribute__((ext_vector_type(4)));

__device__ __forceinline__ unsigned short f2bf(float f) {
  union { float f; unsigned u; } v; v.f = f;
  unsigned r = v.u + 0x7FFFu + ((v.u >> 16) & 1u);
  return (unsigned short)(r >> 16);
}

#define SZ_W0 401408   // 512*784
#define SZ_W1 131072   // 256*512
#define SZ_W2PAD 4096  // 16*256 (zero-padded from 10*256)

__global__ __launch_bounds__(256) void cvt_weights_kernel(
    const float* __restrict__ W0, const float* __restrict__ W1,
    const float* __restrict__ W2,
    unsigned short* __restrict__ W0b, unsigned short* __restrict__ W1b,
    unsigned short* __restrict__ W2b)
{
  int i = blockIdx.x * 256 + threadIdx.x;
  if (i < SZ_W0) { W0b[i] = f2bf(W0[i]); return; }
  i -= SZ_W0;
  if (i < SZ_W1) { W1b[i] = f2bf(W1[i]); return; }
  i -= SZ_W1;
  if (i < SZ_W2PAD) {
    int r = i >> 8, c = i & 255;
    W2b[i] = (r < 10) ? f2bf(W2[r * 256 + c]) : (unsigned short)0;
  }
}

// C = relu(A @ W^T), A:[M,K] (f32 or bf16), W:[N,K] bf16, C:[M,N] bf16.
// 128x128 tile, BK=32, 256 threads = 4 waves in 2x2, each wave 64x64 (4x4 frags).
// Requires: M%128==0, N%128==0, K%8==0 (f32 path: K%4==0).
template<bool A_F32>
__global__ __launch_bounds__(256) void gemm_relu_bf16(
    const void* __restrict__ Ap, const unsigned short* __restrict__ Wp,
    unsigned short* __restrict__ Cp, int M, int N, int K, int ntn)
{
  __shared__ unsigned short As[128][32];
  __shared__ unsigned short Ws[128][32];
  const int t = threadIdx.x;
  const int ct = blockIdx.x % ntn;
  const int rt = blockIdx.x / ntn;
  const size_t rbase = (size_t)rt * 128;
  const size_t cbase = (size_t)ct * 128;

  const int w = t >> 6, lane = t & 63;
  const int wr = w >> 1, wc = w & 1;
  const int fr = lane & 15;       // fragment row (A) / col (B)
  const int fg = lane >> 4;       // k-group: k = fg*8 + j

  f32x4 acc[4][4];
#pragma unroll
  for (int i = 0; i < 4; ++i)
#pragma unroll
    for (int j = 0; j < 4; ++j)
      acc[i][j] = (f32x4){0.f, 0.f, 0.f, 0.f};

  for (int k0 = 0; k0 < K; k0 += 32) {
    __syncthreads();
    // stage W tile (bf16 source): 128 rows x 32 k, 8 elems/thread/pass, 2 passes
#pragma unroll
    for (int p = 0; p < 2; ++p) {
      int r = (t >> 2) + p * 64;
      int kc = (t & 3) * 8;
      int gk = k0 + kc;
      int4 v = make_int4(0, 0, 0, 0);
      if (gk < K) v = *(const int4*)(Wp + (cbase + r) * (size_t)K + gk);
      *(int4*)&Ws[r][kc] = v;
    }
    // stage A tile
    if (A_F32) {
      const float* A = (const float*)Ap;
#pragma unroll
      for (int p = 0; p < 4; ++p) {
        int r = (t >> 3) + p * 32;
        int kc = (t & 7) * 4;
        int gk = k0 + kc;
        float4 v = make_float4(0.f, 0.f, 0.f, 0.f);
        if (gk < K) v = *(const float4*)(A + (rbase + r) * (size_t)K + gk);
        ushort4 b;
        b.x = f2bf(v.x); b.y = f2bf(v.y); b.z = f2bf(v.z); b.w = f2bf(v.w);
        *(ushort4*)&As[r][kc] = b;
      }
    } else {
      const unsigned short* A = (const unsigned short*)Ap;
#pragma unroll
      for (int p = 0; p < 2; ++p) {
        int r = (t >> 2) + p * 64;
        int kc = (t & 3) * 8;
        int gk = k0 + kc;
        int4 v = make_int4(0, 0, 0, 0);
        if (gk < K) v = *(const int4*)(A + (rbase + r) * (size_t)K + gk);
        *(int4*)&As[r][kc] = v;
      }
    }
    __syncthreads();

    bhalf8 af[4], bfr[4];
#pragma unroll
    for (int i = 0; i < 4; ++i)
      af[i] = *(const bhalf8*)&As[wr * 64 + i * 16 + fr][fg * 8];
#pragma unroll
    for (int i = 0; i < 4; ++i)
      bfr[i] = *(const bhalf8*)&Ws[wc * 64 + i * 16 + fr][fg * 8];
#pragma unroll
    for (int i = 0; i < 4; ++i)
#pragma unroll
      for (int j = 0; j < 4; ++j)
        acc[i][j] = __builtin_amdgcn_mfma_f32_16x16x32_bf16(af[i], bfr[j], acc[i][j], 0, 0, 0);
  }

  // epilogue: C/D layout col=lane&15, row=(lane>>4)*4+q
  const size_t crow0 = rbase + (size_t)wr * 64 + fg * 4;
  const size_t ccol0 = cbase + (size_t)wc * 64 + fr;
#pragma unroll
  for (int i = 0; i < 4; ++i)
#pragma unroll
    for (int j = 0; j < 4; ++j)
#pragma unroll
      for (int q = 0; q < 4; ++q) {
        float vv = acc[i][j][q];
        vv = vv > 0.f ? vv : 0.f;
        Cp[(crow0 + i * 16 + q) * (size_t)N + (ccol0 + j * 16)] = f2bf(vv);
      }
}

// Final layer: C[M,10] f32 = relu(A[M,256] bf16 @ W[16,256]^T bf16), cols 10..15 padded.
// One block = 64 rows, 4 waves each computing a 16x16 tile.
__global__ __launch_bounds__(256) void gemm3_kernel(
    const unsigned short* __restrict__ A, const unsigned short* __restrict__ W,
    float* __restrict__ C, int M)
{
  __shared__ unsigned short As[64][264];   // +8 pad: conflict-free b128 reads
  __shared__ unsigned short Wsh[16][264];
  const int t = threadIdx.x;
  const size_t row_base = (size_t)blockIdx.x * 64;

  // stage W: 16*256 elems = 512 groups of 8
#pragma unroll
  for (int p = 0; p < 2; ++p) {
    int g = t + p * 256;
    int r = g >> 5, kc = (g & 31) * 8;
    *(int4*)&Wsh[r][kc] = *(const int4*)(W + r * 256 + kc);
  }
  // stage A: 64*256 elems = 2048 groups of 8
#pragma unroll
  for (int p = 0; p < 8; ++p) {
    int g = t + p * 256;
    int r = g >> 5, kc = (g & 31) * 8;
    *(int4*)&As[r][kc] = *(const int4*)(A + (row_base + r) * 256 + kc);
  }
  __syncthreads();

  const int w = t >> 6, lane = t & 63;
  const int fr = lane & 15, fg = lane >> 4;
  const int arow = w * 16 + fr;

  f32x4 acc = (f32x4){0.f, 0.f, 0.f, 0.f};
#pragma unroll
  for (int ks = 0; ks < 8; ++ks) {
    bhalf8 a = *(const bhalf8*)&As[arow][ks * 32 + fg * 8];
    bhalf8 b = *(const bhalf8*)&Wsh[fr][ks * 32 + fg * 8];
    acc = __builtin_amdgcn_mfma_f32_16x16x32_bf16(a, b, acc, 0, 0, 0);
  }

  const int col = fr;
  if (col < 10) {
#pragma unroll
    for (int q = 0; q < 4; ++q) {
      int r = w * 16 + fg * 4 + q;
      float vv = acc[q];
      C[(row_base + r) * 10 + col] = vv > 0.f ? vv : 0.f;
    }
  }
}

extern "C" void kernel_launch(void* const* d_in, const int* in_sizes, int n_in,
                              void* d_out, int out_size, void* d_ws, size_t ws_size,
                              hipStream_t stream) {
  const float* x  = (const float*)d_in[0];
  const float* W0 = (const float*)d_in[1];
  const float* W1 = (const float*)d_in[2];
  const float* W2 = (const float*)d_in[3];
  float* out = (float*)d_out;

  char* ws = (char*)d_ws;
  unsigned short* m1  = (unsigned short*)(ws);                       // 32768x512 bf16 = 32 MB
  unsigned short* m2  = (unsigned short*)(ws + 33554432);            // 32768x256 bf16 = 16 MB
  unsigned short* W0b = (unsigned short*)(ws + 50331648);            // 512x784
  unsigned short* W1b = (unsigned short*)(ws + 51134464);            // 256x512
  unsigned short* W2b = (unsigned short*)(ws + 51396608);            // 16x256 padded

  // convert weights to bf16
  cvt_weights_kernel<<<(SZ_W0 + SZ_W1 + SZ_W2PAD + 255) / 256, 256, 0, stream>>>(
      W0, W1, W2, W0b, W1b, W2b);

  // m1 = relu(x @ W0^T)  [32768,512], K=784
  gemm_relu_bf16<true><<<dim3(256 * 4), dim3(256), 0, stream>>>(
      (const void*)x, W0b, m1, 32768, 512, 784, 4);

  // m2 = relu(m1 @ W1^T) [32768,256], K=512
  gemm_relu_bf16<false><<<dim3(256 * 2), dim3(256), 0, stream>>>(
      (const void*)m1, W1b, m2, 32768, 256, 512, 2);

  // out = relu(m2 @ W2^T) [32768,10], K=256
  gemm3_kernel<<<dim3(512), dim3(256), 0, stream>>>(m2, W2b, out, 32768);
}

// Round 2
// 90.740 us; speedup vs baseline: 1.3950x; 1.3950x over previous
//
#include <hip/hip_runtime.h>

typedef __bf16 bhalf;
typedef bhalf bhalf8 __attribute__((ext_vector_type(8)));
typedef float f32x4 __attribute__((ext_vector_type(4)));
typedef unsigned short u16;
typedef u16 u16x8 __attribute__((ext_vector_type(8)));

__device__ __forceinline__ u16 f2bf(float f) {
  union { float f; unsigned u; } v; v.f = f;
  unsigned r = v.u + 0x7FFFu + ((v.u >> 16) & 1u);
  return (u16)(r >> 16);
}

#define GLL16(gp, lp) __builtin_amdgcn_global_load_lds( \
    (const __attribute__((address_space(1))) unsigned int*)(gp), \
    (__attribute__((address_space(3))) unsigned int*)(lp), 16, 0, 0)

// W0: [512][784] -> bf16 [512][800] zero-padded; W1: [256][512]; W2: [10][256] -> [16][256] padded.
#define W0E (512 * 800)
#define W1E (256 * 512)
#define W2E (16 * 256)

__global__ __launch_bounds__(256) void cvt_weights(
    const float* __restrict__ W0, const float* __restrict__ W1,
    const float* __restrict__ W2,
    u16* __restrict__ W0b, u16* __restrict__ W1b, u16* __restrict__ W2b)
{
  int i = blockIdx.x * 256 + threadIdx.x;
  if (i < W0E) {
    int r = i / 800, k = i - r * 800;
    W0b[i] = (k < 784) ? f2bf(W0[r * 784 + k]) : (u16)0;
    return;
  }
  i -= W0E;
  if (i < W1E) { W1b[i] = f2bf(W1[i]); return; }
  i -= W1E;
  if (i < W2E) {
    int r = i >> 8, c = i & 255;
    W2b[i] = (r < 10) ? f2bf(W2[r * 256 + c]) : (u16)0;
  }
}

// C = relu(A @ W^T) as bf16. Tile: BM x 256, BK=32, 8 waves (2Mx4N), double-buffered LDS,
// one barrier per K-step, T14 async staging, T2 XOR-swizzled LDS (phys = U ^ (((U>>7)&7)<<4)).
// A_F32: A is f32, reg-staged + converted; else A is bf16 via global_load_lds.
// MF = M-fragments per wave (wave tile = MF*16 x 64); BM = MF*32.
template<bool A_F32, int MF>
__global__ __launch_bounds__(512) void gemm2p(
    const void* __restrict__ Ap, const u16* __restrict__ Wb, u16* __restrict__ Cp,
    int N, int Ktrue, int Kpad, int ntn)
{
  constexpr int BM = MF * 32;
  constexpr int CA = (BM * 4) / 512;   // per-thread A chunks (f32) / per-wave A gll issues (bf16)
  __shared__ u16 As[2][BM * 32];
  __shared__ u16 Bs[2][256 * 32];

  const int t = threadIdx.x;
  const int w = t >> 6, lane = t & 63;
  const int rt = blockIdx.x / ntn, ct = blockIdx.x % ntn;
  const size_t rbase = (size_t)rt * BM;
  const size_t cbase = (size_t)ct * 256;
  const int wr = w >> 2, wc = w & 3;
  const int fr = lane & 15, fg = lane >> 4;
  const int nk = Kpad >> 5;

  // loop-invariant swizzled fragment-read byte offsets
  int aOff[MF], bOff[4];
#pragma unroll
  for (int i = 0; i < MF; ++i) {
    int row = wr * (MF * 16) + i * 16 + fr;
    int U = row * 64 + fg * 16;
    aOff[i] = U ^ (((U >> 7) & 7) << 4);
  }
#pragma unroll
  for (int j = 0; j < 4; ++j) {
    int row = wc * 64 + j * 16 + fr;
    int U = row * 64 + fg * 16;
    bOff[j] = U ^ (((U >> 7) & 7) << 4);
  }

  // B staging: 2 x 1KB global_load_lds per wave; source pre-swizzled
  const u16* bSrc[2];
#pragma unroll
  for (int i = 0; i < 2; ++i) {
    int Dl = (w * 128 + i * 64 + lane) * 16;
    int Ul = Dl ^ (((Dl >> 7) & 7) << 4);
    int row = Ul >> 6, ke = (Ul & 63) >> 1;
    bSrc[i] = Wb + (cbase + row) * (size_t)Kpad + ke;
  }

  // A staging meta
  const float* aSrcF[CA];
  const u16*  aSrcB[CA];
  int aDl[CA], aKe[CA];
  if constexpr (A_F32) {
    const float* Ax = (const float*)Ap;
#pragma unroll
    for (int p = 0; p < CA; ++p) {
      int Dl = (p * 512 + t) * 16;
      int Ul = Dl ^ (((Dl >> 7) & 7) << 4);
      int row = Ul >> 6, ke = (Ul & 63) >> 1;
      aDl[p] = Dl; aKe[p] = ke;
      aSrcF[p] = Ax + (rbase + row) * (size_t)Ktrue + ke;
    }
  } else {
    const u16* Ax = (const u16*)Ap;
#pragma unroll
    for (int p = 0; p < CA; ++p) {
      int Dl = (w * (CA * 64) + p * 64 + lane) * 16;
      int Ul = Dl ^ (((Dl >> 7) & 7) << 4);
      int row = Ul >> 6, ke = (Ul & 63) >> 1;
      aDl[p] = (w * (CA * 64) + p * 64) * 16;   // wave-uniform LDS dest base
      aSrcB[p] = Ax + (rbase + row) * (size_t)Kpad + ke;
    }
  }

  f32x4 acc[MF][4];
#pragma unroll
  for (int i = 0; i < MF; ++i)
#pragma unroll
    for (int j = 0; j < 4; ++j) acc[i][j] = (f32x4){0.f, 0.f, 0.f, 0.f};

  f32x4 areg[CA][2];

  // ---- prologue: stage tile 0 into buffer 0 ----
  if constexpr (A_F32) {
#pragma unroll
    for (int p = 0; p < CA; ++p) {
      f32x4 z = (f32x4){0.f, 0.f, 0.f, 0.f};
      f32x4 v0 = z, v1 = z;
      if (aKe[p] < Ktrue) { v0 = *(const f32x4*)(aSrcF[p]); v1 = *(const f32x4*)(aSrcF[p] + 4); }
      areg[p][0] = v0; areg[p][1] = v1;
    }
  } else {
#pragma unroll
    for (int p = 0; p < CA; ++p) GLL16(aSrcB[p], (char*)As[0] + aDl[p]);
  }
#pragma unroll
  for (int i = 0; i < 2; ++i) GLL16(bSrc[i], (char*)Bs[0] + (w * 128 + i * 64) * 16);

  for (int tt = 0; tt < nk; ++tt) {
    const int cur = tt & 1, nxt = cur ^ 1;

    if constexpr (A_F32) {
      // convert tile tt's A (in regs) and write to LDS (compiler waits the loads)
#pragma unroll
      for (int p = 0; p < CA; ++p) {
        u16x8 v;
#pragma unroll
        for (int j = 0; j < 4; ++j) { v[j] = f2bf(areg[p][0][j]); v[4 + j] = f2bf(areg[p][1][j]); }
        *(u16x8*)((char*)As[cur] + aDl[p]) = v;
      }
    }
    asm volatile("s_waitcnt vmcnt(0)" ::: "memory");  // global_load_lds arrivals
    __syncthreads();

    if (tt + 1 < nk) {
      const int k0n = (tt + 1) << 5;
      if constexpr (A_F32) {
#pragma unroll
        for (int p = 0; p < CA; ++p) {
          f32x4 z = (f32x4){0.f, 0.f, 0.f, 0.f};
          f32x4 v0 = z, v1 = z;
          int gk = k0n + aKe[p];
          if (gk < Ktrue) {
            v0 = *(const f32x4*)(aSrcF[p] + k0n);
            v1 = *(const f32x4*)(aSrcF[p] + k0n + 4);
          }
          areg[p][0] = v0; areg[p][1] = v1;
        }
      } else {
#pragma unroll
        for (int p = 0; p < CA; ++p) GLL16(aSrcB[p] + k0n, (char*)As[nxt] + aDl[p]);
      }
#pragma unroll
      for (int i = 0; i < 2; ++i) GLL16(bSrc[i] + k0n, (char*)Bs[nxt] + (w * 128 + i * 64) * 16);
    }

    bhalf8 af[MF], bfv[4];
#pragma unroll
    for (int i = 0; i < MF; ++i) af[i] = *(const bhalf8*)((const char*)As[cur] + aOff[i]);
#pragma unroll
    for (int j = 0; j < 4; ++j) bfv[j] = *(const bhalf8*)((const char*)Bs[cur] + bOff[j]);
#pragma unroll
    for (int i = 0; i < MF; ++i)
#pragma unroll
      for (int j = 0; j < 4; ++j)
        acc[i][j] = __builtin_amdgcn_mfma_f32_16x16x32_bf16(af[i], bfv[j], acc[i][j], 0, 0, 0);
  }

  // epilogue: C/D layout col=lane&15, row=(lane>>4)*4+q
#pragma unroll
  for (int i = 0; i < MF; ++i)
#pragma unroll
    for (int j = 0; j < 4; ++j)
#pragma unroll
      for (int q = 0; q < 4; ++q) {
        size_t row = rbase + wr * (MF * 16) + i * 16 + fg * 4 + q;
        size_t col = cbase + wc * 64 + j * 16 + fr;
        float vv = acc[i][j][q];
        vv = vv > 0.f ? vv : 0.f;
        Cp[row * N + col] = f2bf(vv);
      }
}

// Final layer: C[M,10] f32 = relu(A[M,256] bf16 @ W[16,256]^T bf16), cols 10..15 padded.
__global__ __launch_bounds__(256) void gemm3_kernel(
    const u16* __restrict__ A, const u16* __restrict__ W,
    float* __restrict__ C, int M)
{
  __shared__ u16 As[64][264];
  __shared__ u16 Wsh[16][264];
  const int t = threadIdx.x;
  const size_t row_base = (size_t)blockIdx.x * 64;

#pragma unroll
  for (int p = 0; p < 2; ++p) {
    int g = t + p * 256;
    int r = g >> 5, kc = (g & 31) * 8;
    *(int4*)&Wsh[r][kc] = *(const int4*)(W + r * 256 + kc);
  }
#pragma unroll
  for (int p = 0; p < 8; ++p) {
    int g = t + p * 256;
    int r = g >> 5, kc = (g & 31) * 8;
    *(int4*)&As[r][kc] = *(const int4*)(A + (row_base + r) * 256 + kc);
  }
  __syncthreads();

  const int w = t >> 6, lane = t & 63;
  const int fr = lane & 15, fg = lane >> 4;
  const int arow = w * 16 + fr;

  f32x4 acc = (f32x4){0.f, 0.f, 0.f, 0.f};
#pragma unroll
  for (int ks = 0; ks < 8; ++ks) {
    bhalf8 a = *(const bhalf8*)&As[arow][ks * 32 + fg * 8];
    bhalf8 b = *(const bhalf8*)&Wsh[fr][ks * 32 + fg * 8];
    acc = __builtin_amdgcn_mfma_f32_16x16x32_bf16(a, b, acc, 0, 0, 0);
  }

  const int col = fr;
  if (col < 10) {
#pragma unroll
    for (int q = 0; q < 4; ++q) {
      int r = w * 16 + fg * 4 + q;
      float vv = acc[q];
      C[(row_base + r) * 10 + col] = vv > 0.f ? vv : 0.f;
    }
  }
}

extern "C" void kernel_launch(void* const* d_in, const int* in_sizes, int n_in,
                              void* d_out, int out_size, void* d_ws, size_t ws_size,
                              hipStream_t stream) {
  const float* x  = (const float*)d_in[0];
  const float* W0 = (const float*)d_in[1];
  const float* W1 = (const float*)d_in[2];
  const float* W2 = (const float*)d_in[3];
  float* out = (float*)d_out;

  char* ws = (char*)d_ws;
  u16* m1  = (u16*)(ws);                    // 32768x512 bf16 = 33554432 B
  u16* m2  = (u16*)(ws + 33554432);         // 32768x256 bf16 = 16777216 B
  u16* W0b = (u16*)(ws + 50331648);         // 512x800 bf16   = 819200 B
  u16* W1b = (u16*)(ws + 51150848);         // 256x512 bf16   = 262144 B
  u16* W2b = (u16*)(ws + 51412992);         // 16x256 bf16    = 8192 B

  cvt_weights<<<dim3((W0E + W1E + W2E + 255) / 256), dim3(256), 0, stream>>>(
      W0, W1, W2, W0b, W1b, W2b);

  // m1 = relu(x @ W0^T): M=32768 (BM=256 -> 128 row tiles), N=512 (2 col tiles), K=784 pad 800
  gemm2p<true, 8><<<dim3(128 * 2), dim3(512), 0, stream>>>(
      (const void*)x, W0b, m1, 512, 784, 800, 2);

  // m2 = relu(m1 @ W1^T): M=32768 (BM=128 -> 256 row tiles), N=256 (1 col tile), K=512
  gemm2p<false, 4><<<dim3(256), dim3(512), 0, stream>>>(
      (const void*)m1, W1b, m2, 256, 512, 512, 1);

  // out = relu(m2 @ W2^T): [32768,10] f32
  gemm3_kernel<<<dim3(512), dim3(256), 0, stream>>>(m2, W2b, out, 32768);
}

// Round 4
// 74.675 us; speedup vs baseline: 1.6951x; 1.2151x over previous
//
#include <hip/hip_runtime.h>

typedef __bf16 bhalf;
typedef bhalf bhalf8 __attribute__((ext_vector_type(8)));
typedef float f32x4 __attribute__((ext_vector_type(4)));
typedef unsigned short u16;
typedef u16 u16x8 __attribute__((ext_vector_type(8)));

__device__ __forceinline__ u16 f2bf(float f) {
  union { float f; unsigned u; } v; v.f = f;
  unsigned r = v.u + 0x7FFFu + ((v.u >> 16) & 1u);
  return (u16)(r >> 16);
}

// XOR swizzle for [R][64]-bf16 (128B-row) LDS tiles; involution, keys on row&7.
__device__ __forceinline__ int swz(int L) { return L ^ (((L >> 7) & 7) << 4); }

#define GLL16(gp, lp) __builtin_amdgcn_global_load_lds( \
    (const __attribute__((address_space(1))) unsigned int*)(gp), \
    (__attribute__((address_space(3))) unsigned int*)(lp), 16, 0, 0)

// W0: [512][784] f32 -> bf16 [512][832] zero-pad; W1: [256][512]; W2: [10][256] -> [16][256] pad.
#define W0E (512 * 832)
#define W1E (256 * 512)
#define W2E (16 * 256)

__global__ __launch_bounds__(256) void cvt_weights(
    const float* __restrict__ W0, const float* __restrict__ W1,
    const float* __restrict__ W2,
    u16* __restrict__ W0b, u16* __restrict__ W1b, u16* __restrict__ W2b)
{
  int i = blockIdx.x * 256 + threadIdx.x;
  if (i < W0E) {
    int r = i / 832, k = i - r * 832;
    W0b[i] = (k < 784) ? f2bf(W0[r * 784 + k]) : (u16)0;
    return;
  }
  i -= W0E;
  if (i < W1E) { W1b[i] = f2bf(W1[i]); return; }
  i -= W1E;
  if (i < W2E) {
    int r = i >> 8, c = i & 255;
    W2b[i] = (r < 10) ? f2bf(W2[r * 256 + c]) : (u16)0;
  }
}

// m1 = relu(x @ W0^T) bf16. 128x128 tile, BK=64, 4 waves (2x2), dbuf LDS 64KB -> 2 blocks/CU.
// A: f32 reg-staged + cvt (T14); B: global_load_lds pre-swizzled. K=784 pad 832 (13 steps).
__global__ __launch_bounds__(256) void gemm1(
    const float* __restrict__ x, const u16* __restrict__ Wb, u16* __restrict__ Cp)
{
  __shared__ u16 As[2][8192];   // 128 x 64 bf16 = 16 KiB per buffer
  __shared__ u16 Bs[2][8192];
  const int t = threadIdx.x, w = t >> 6, lane = t & 63;
  const int bid = blockIdx.x;
  // XCD-aware: 4 col-tiles of one row-tile land on the same XCD (bid mod 8 fixed).
  const int rt = (bid & 7) + ((bid >> 5) << 3);
  const int ct = (bid >> 3) & 3;
  const size_t rbase = (size_t)rt * 128, cbase = (size_t)ct * 128;
  const int wr = w >> 1, wc = w & 1, fr = lane & 15, fg = lane >> 4;

  int aOff[4], bOff[4];
#pragma unroll
  for (int i = 0; i < 4; ++i) aOff[i] = swz((wr * 64 + i * 16 + fr) * 128 + fg * 16);
#pragma unroll
  for (int j = 0; j < 4; ++j) bOff[j] = swz((wc * 64 + j * 16 + fr) * 128 + fg * 16);

  // B staging via gll, source pre-swizzled
  const u16* bSrc[4]; int bDst[4];
#pragma unroll
  for (int i = 0; i < 4; ++i) {
    int Dl = (w * 256 + i * 64 + lane) * 16;
    int Ul = swz(Dl);
    bSrc[i] = Wb + (cbase + (Ul >> 7)) * 832 + ((Ul & 127) >> 1);
    bDst[i] = (w * 256 + i * 64) * 16;
  }

  // A reg-stage meta (4 chunks of 16B bf16 = 8 f32 each)
  int aRow[4], aKe[4], aDst[4];
#pragma unroll
  for (int c = 0; c < 4; ++c) {
    int P = (c * 256 + t) * 16;
    int Lg = swz(P);
    aRow[c] = Lg >> 7; aKe[c] = (Lg & 127) >> 1; aDst[c] = P;
  }

  f32x4 acc[4][4];
#pragma unroll
  for (int i = 0; i < 4; ++i)
#pragma unroll
    for (int j = 0; j < 4; ++j) acc[i][j] = (f32x4){0.f, 0.f, 0.f, 0.f};

  f32x4 areg[4][2];

  // prologue: tile 0
#pragma unroll
  for (int c = 0; c < 4; ++c) {
    const float* p = x + (rbase + aRow[c]) * (size_t)784 + aKe[c];
    areg[c][0] = *(const f32x4*)p; areg[c][1] = *(const f32x4*)(p + 4);
  }
#pragma unroll
  for (int i = 0; i < 4; ++i) GLL16(bSrc[i], (char*)Bs[0] + bDst[i]);

  for (int tt = 0; tt < 13; ++tt) {
    const int cur = tt & 1;
    // convert + write A tile (compiler waits the pending A loads here)
#pragma unroll
    for (int c = 0; c < 4; ++c) {
      u16x8 v;
#pragma unroll
      for (int j = 0; j < 4; ++j) { v[j] = f2bf(areg[c][0][j]); v[4 + j] = f2bf(areg[c][1][j]); }
      *(u16x8*)((char*)As[cur] + aDst[c]) = v;
    }
    asm volatile("s_waitcnt vmcnt(0)" ::: "memory");   // B gll for cur arrived
    __syncthreads();

    if (tt < 12) {
      const int k0 = (tt + 1) * 64;
#pragma unroll
      for (int c = 0; c < 4; ++c) {
        int k = k0 + aKe[c];
        int koff = (k < 784) ? k : 0;                  // clamp: B zero-padded there
        const float* p = x + (rbase + aRow[c]) * (size_t)784 + koff;
        areg[c][0] = *(const f32x4*)p; areg[c][1] = *(const f32x4*)(p + 4);
      }
#pragma unroll
      for (int i = 0; i < 4; ++i) GLL16(bSrc[i] + k0, (char*)Bs[cur ^ 1] + bDst[i]);
    }

#pragma unroll
    for (int s = 0; s < 2; ++s) {
      bhalf8 af[4], bfv[4];
#pragma unroll
      for (int i = 0; i < 4; ++i) af[i] = *(const bhalf8*)((const char*)As[cur] + (aOff[i] ^ (s << 6)));
#pragma unroll
      for (int j = 0; j < 4; ++j) bfv[j] = *(const bhalf8*)((const char*)Bs[cur] + (bOff[j] ^ (s << 6)));
#pragma unroll
      for (int i = 0; i < 4; ++i)
#pragma unroll
        for (int j = 0; j < 4; ++j)
          acc[i][j] = __builtin_amdgcn_mfma_f32_16x16x32_bf16(af[i], bfv[j], acc[i][j], 0, 0, 0);
    }
  }

#pragma unroll
  for (int i = 0; i < 4; ++i)
#pragma unroll
    for (int j = 0; j < 4; ++j)
#pragma unroll
      for (int q = 0; q < 4; ++q) {
        size_t row = rbase + wr * 64 + i * 16 + fg * 4 + q;
        size_t col = cbase + wc * 64 + j * 16 + fr;
        float vv = acc[i][j][q];
        vv = vv > 0.f ? vv : 0.f;
        Cp[row * 512 + col] = f2bf(vv);
      }
}

// Fused layers 2+3: block = 128 rows x full 256 cols of m2 (in regs) -> relu/bf16 in LDS
// -> layer3 MFMA vs W2 -> out f32 [M,10]. 8 waves (2x4), BK=64, 8 steps, all-gll dbuf.
__global__ __launch_bounds__(512) void gemm23(
    const u16* __restrict__ m1, const u16* __restrict__ W1b,
    const u16* __restrict__ W2b, float* __restrict__ out)
{
  __shared__ u16 pool[49152];          // [2][128x64] A | [2][256x64] B; reused as m2 [128][264]
  __shared__ u16 W2s[16][264];
  const int t = threadIdx.x, w = t >> 6, lane = t & 63;
  const size_t rbase = (size_t)blockIdx.x * 128;
  const int wr = w >> 2, wc = w & 3, fr = lane & 15, fg = lane >> 4;

  // stage W2 once (16x256, 512 chunks of 8)
  {
    int r = t >> 5, kc = (t & 31) * 8;
    *(int4*)&W2s[r][kc] = *(const int4*)(W2b + r * 256 + kc);
  }

  int aOff[4], bOff[4];
#pragma unroll
  for (int i = 0; i < 4; ++i) aOff[i] = swz((wr * 64 + i * 16 + fr) * 128 + fg * 16);
#pragma unroll
  for (int j = 0; j < 4; ++j) bOff[j] = swz((wc * 64 + j * 16 + fr) * 128 + fg * 16);

  const u16* aSrc[2]; int aDst[2];
#pragma unroll
  for (int i = 0; i < 2; ++i) {
    int Dl = (w * 128 + i * 64 + lane) * 16;
    int Ul = swz(Dl);
    aSrc[i] = m1 + (rbase + (Ul >> 7)) * 512 + ((Ul & 127) >> 1);
    aDst[i] = (w * 128 + i * 64) * 16;
  }
  const u16* bSrc[4]; int bDst[4];
#pragma unroll
  for (int i = 0; i < 4; ++i) {
    int Dl = (w * 256 + i * 64 + lane) * 16;
    int Ul = swz(Dl);
    bSrc[i] = W1b + (Ul >> 7) * 512 + ((Ul & 127) >> 1);
    bDst[i] = (w * 256 + i * 64) * 16;
  }

  f32x4 acc[4][4];
#pragma unroll
  for (int i = 0; i < 4; ++i)
#pragma unroll
    for (int j = 0; j < 4; ++j) acc[i][j] = (f32x4){0.f, 0.f, 0.f, 0.f};

  // prologue: tile 0 into buf0
#pragma unroll
  for (int i = 0; i < 2; ++i) GLL16(aSrc[i], (char*)(pool) + aDst[i]);
#pragma unroll
  for (int i = 0; i < 4; ++i) GLL16(bSrc[i], (char*)(pool + 16384) + bDst[i]);

  for (int tt = 0; tt < 8; ++tt) {
    const int cur = tt & 1;
    u16* Asc = pool + cur * 8192;
    u16* Bsc = pool + 16384 + cur * 16384;
    asm volatile("s_waitcnt vmcnt(0)" ::: "memory");
    __syncthreads();

    if (tt < 7) {
      const int k0 = (tt + 1) * 64;
      u16* Asn = pool + (cur ^ 1) * 8192;
      u16* Bsn = pool + 16384 + (cur ^ 1) * 16384;
#pragma unroll
      for (int i = 0; i < 2; ++i) GLL16(aSrc[i] + k0, (char*)Asn + aDst[i]);
#pragma unroll
      for (int i = 0; i < 4; ++i) GLL16(bSrc[i] + k0, (char*)Bsn + bDst[i]);
    }

#pragma unroll
    for (int s = 0; s < 2; ++s) {
      bhalf8 af[4], bfv[4];
#pragma unroll
      for (int i = 0; i < 4; ++i) af[i] = *(const bhalf8*)((const char*)Asc + (aOff[i] ^ (s << 6)));
#pragma unroll
      for (int j = 0; j < 4; ++j) bfv[j] = *(const bhalf8*)((const char*)Bsc + (bOff[j] ^ (s << 6)));
#pragma unroll
      for (int i = 0; i < 4; ++i)
#pragma unroll
        for (int j = 0; j < 4; ++j)
          acc[i][j] = __builtin_amdgcn_mfma_f32_16x16x32_bf16(af[i], bfv[j], acc[i][j], 0, 0, 0);
    }
  }

  __syncthreads();                       // everyone done reading staging LDS
  // m2 = relu(acc) -> bf16 into pool as [128][264]
#pragma unroll
  for (int i = 0; i < 4; ++i)
#pragma unroll
    for (int j = 0; j < 4; ++j)
#pragma unroll
      for (int q = 0; q < 4; ++q) {
        int row = wr * 64 + i * 16 + fg * 4 + q;
        int col = wc * 64 + j * 16 + fr;
        float vv = acc[i][j][q];
        vv = vv > 0.f ? vv : 0.f;
        pool[row * 264 + col] = f2bf(vv);
      }
  __syncthreads();

  // layer 3: wave w handles rows w*16..w*16+15; K=256 (8 ksubs)
  f32x4 acc3 = (f32x4){0.f, 0.f, 0.f, 0.f};
  const int arow = w * 16 + fr;
#pragma unroll
  for (int ks = 0; ks < 8; ++ks) {
    bhalf8 a = *(const bhalf8*)&pool[arow * 264 + ks * 32 + fg * 8];
    bhalf8 b = *(const bhalf8*)&W2s[fr][ks * 32 + fg * 8];
    acc3 = __builtin_amdgcn_mfma_f32_16x16x32_bf16(a, b, acc3, 0, 0, 0);
  }
  if (fr < 10) {
#pragma unroll
    for (int q = 0; q < 4; ++q) {
      size_t row = rbase + w * 16 + fg * 4 + q;
      float vv = acc3[q];
      out[row * 10 + fr] = vv > 0.f ? vv : 0.f;
    }
  }
}

extern "C" void kernel_launch(void* const* d_in, const int* in_sizes, int n_in,
                              void* d_out, int out_size, void* d_ws, size_t ws_size,
                              hipStream_t stream) {
  const float* x  = (const float*)d_in[0];
  const float* W0 = (const float*)d_in[1];
  const float* W1 = (const float*)d_in[2];
  const float* W2 = (const float*)d_in[3];
  float* out = (float*)d_out;

  char* ws = (char*)d_ws;
  u16* m1  = (u16*)(ws);                    // 32768x512 bf16 = 33554432 B
  u16* W0b = (u16*)(ws + 33554432);         // 512x832 = 851968 B
  u16* W1b = (u16*)(ws + 34406400);         // 256x512 = 262144 B
  u16* W2b = (u16*)(ws + 34668544);         // 16x256  = 8192 B

  cvt_weights<<<dim3((W0E + W1E + W2E + 255) / 256), dim3(256), 0, stream>>>(
      W0, W1, W2, W0b, W1b, W2b);

  // m1 = relu(x @ W0^T): 256 row tiles x 4 col tiles
  gemm1<<<dim3(1024), dim3(256), 0, stream>>>(x, W0b, m1);

  // out = relu(relu(m1 @ W1^T) @ W2^T): fused layers 2+3
  gemm23<<<dim3(256), dim3(512), 0, stream>>>(m1, W1b, W2b, out);
}

// Round 5
// 70.333 us; speedup vs baseline: 1.7998x; 1.0617x over previous
//
#include <hip/hip_runtime.h>

typedef __bf16 bhalf;
typedef bhalf bhalf8 __attribute__((ext_vector_type(8)));
typedef float f32x4 __attribute__((ext_vector_type(4)));
typedef unsigned short u16;
typedef u16 u16x8 __attribute__((ext_vector_type(8)));

__device__ __forceinline__ u16 f2bf(float f) {
  union { float f; unsigned u; } v; v.f = f;
  unsigned r = v.u + 0x7FFFu + ((v.u >> 16) & 1u);
  return (u16)(r >> 16);
}

// XOR swizzle keyed on bits 7-9 (row-pair for 64B rows); involution; <=2-way banks.
__device__ __forceinline__ int swz(int L) { return L ^ (((L >> 7) & 7) << 4); }

#define GLL16(gp, lp) __builtin_amdgcn_global_load_lds( \
    (const __attribute__((address_space(1))) unsigned int*)(gp), \
    (__attribute__((address_space(3))) unsigned int*)(lp), 16, 0, 0)

// W0: [512][784] f32 -> bf16 [512][832] zero-pad; W1: [256][512]; W2: [10][256] -> [16][256] pad.
#define W0E (512 * 832)
#define W1E (256 * 512)
#define W2E (16 * 256)

__global__ __launch_bounds__(256) void cvt_weights(
    const float* __restrict__ W0, const float* __restrict__ W1,
    const float* __restrict__ W2,
    u16* __restrict__ W0b, u16* __restrict__ W1b, u16* __restrict__ W2b)
{
  int i = blockIdx.x * 256 + threadIdx.x;
  if (i < W0E) {
    int r = i / 832, k = i - r * 832;
    W0b[i] = (k < 784) ? f2bf(W0[r * 784 + k]) : (u16)0;
    return;
  }
  i -= W0E;
  if (i < W1E) { W1b[i] = f2bf(W1[i]); return; }
  i -= W1E;
  if (i < W2E) {
    int r = i >> 8, c = i & 255;
    W2b[i] = (r < 10) ? f2bf(W2[r * 256 + c]) : (u16)0;
  }
}

// m1 = relu(x @ W0^T) bf16. 128x128 tile, BK=32, 4 waves (2x2), dbuf LDS 32KB.
// __launch_bounds__(256,4): VGPR<=128 -> 4 blocks/CU resident (grid 1024 = 4/CU).
// A: f32 reg-staged + cvt; B: global_load_lds pre-swizzled. K=784 pad 832 (26 steps).
__global__ __launch_bounds__(256, 4) void gemm1(
    const float* __restrict__ x, const u16* __restrict__ Wb, u16* __restrict__ Cp)
{
  __shared__ u16 As[2][4096];   // 128 x 32 bf16 = 8 KiB per buffer
  __shared__ u16 Bs[2][4096];
  const int t = threadIdx.x, w = t >> 6, lane = t & 63;
  const int bid = blockIdx.x;
  // XCD-aware: 4 col-tiles of one row-tile land on the same XCD (bid mod 8 fixed).
  const int rt = (bid & 7) + ((bid >> 5) << 3);
  const int ct = (bid >> 3) & 3;
  const size_t rbase = (size_t)rt * 128, cbase = (size_t)ct * 128;
  const int wr = w >> 1, wc = w & 1, fr = lane & 15, fg = lane >> 4;

  // fragment-read byte offsets into [128][32] (64B rows)
  int aOff[4], bOff[4];
#pragma unroll
  for (int i = 0; i < 4; ++i) aOff[i] = swz((wr * 64 + i * 16 + fr) * 64 + fg * 16);
#pragma unroll
  for (int j = 0; j < 4; ++j) bOff[j] = swz((wc * 64 + j * 16 + fr) * 64 + fg * 16);

  // B staging: 8KB tile = 2 x 1KB GLL per wave; source pre-swizzled
  const u16* bSrc[2]; int bDst[2];
#pragma unroll
  for (int i = 0; i < 2; ++i) {
    int Dl = (w * 128 + i * 64 + lane) * 16;
    int Ul = swz(Dl);
    bSrc[i] = Wb + (cbase + (Ul >> 6)) * 832 + ((Ul & 63) >> 1);
    bDst[i] = (w * 128 + i * 64) * 16;
  }

  // A reg-stage meta: 2 chunks of 16B (8 f32 reads each) per thread
  int aRow[2], aKe[2], aDst[2];
#pragma unroll
  for (int c = 0; c < 2; ++c) {
    int P = c * 4096 + t * 16;
    int Lg = swz(P);
    aRow[c] = Lg >> 6; aKe[c] = (Lg & 63) >> 1; aDst[c] = P;
  }

  f32x4 acc[4][4];
#pragma unroll
  for (int i = 0; i < 4; ++i)
#pragma unroll
    for (int j = 0; j < 4; ++j) acc[i][j] = (f32x4){0.f, 0.f, 0.f, 0.f};

  f32x4 areg[2][2];

  // prologue: tile 0
#pragma unroll
  for (int c = 0; c < 2; ++c) {
    const float* p = x + (rbase + aRow[c]) * (size_t)784 + aKe[c];
    areg[c][0] = *(const f32x4*)p; areg[c][1] = *(const f32x4*)(p + 4);
  }
#pragma unroll
  for (int i = 0; i < 2; ++i) GLL16(bSrc[i], (char*)Bs[0] + bDst[i]);

  for (int tt = 0; tt < 26; ++tt) {
    const int cur = tt & 1;
    // convert + write A tile (compiler waits the pending A loads here)
#pragma unroll
    for (int c = 0; c < 2; ++c) {
      u16x8 v;
#pragma unroll
      for (int j = 0; j < 4; ++j) { v[j] = f2bf(areg[c][0][j]); v[4 + j] = f2bf(areg[c][1][j]); }
      *(u16x8*)((char*)As[cur] + aDst[c]) = v;
    }
    asm volatile("s_waitcnt vmcnt(0)" ::: "memory");   // B gll for cur arrived
    __syncthreads();

    if (tt < 25) {
      const int k0 = (tt + 1) * 32;
#pragma unroll
      for (int c = 0; c < 2; ++c) {
        int k = k0 + aKe[c];
        int koff = (k < 784) ? k : 0;                  // clamp: W0b zero-padded there
        const float* p = x + (rbase + aRow[c]) * (size_t)784 + koff;
        areg[c][0] = *(const f32x4*)p; areg[c][1] = *(const f32x4*)(p + 4);
      }
#pragma unroll
      for (int i = 0; i < 2; ++i) GLL16(bSrc[i] + k0, (char*)Bs[cur ^ 1] + bDst[i]);
    }

    bhalf8 af[4], bfv[4];
#pragma unroll
    for (int i = 0; i < 4; ++i) af[i] = *(const bhalf8*)((const char*)As[cur] + aOff[i]);
#pragma unroll
    for (int j = 0; j < 4; ++j) bfv[j] = *(const bhalf8*)((const char*)Bs[cur] + bOff[j]);
#pragma unroll
    for (int i = 0; i < 4; ++i)
#pragma unroll
      for (int j = 0; j < 4; ++j)
        acc[i][j] = __builtin_amdgcn_mfma_f32_16x16x32_bf16(af[i], bfv[j], acc[i][j], 0, 0, 0);
  }

#pragma unroll
  for (int i = 0; i < 4; ++i)
#pragma unroll
    for (int j = 0; j < 4; ++j)
#pragma unroll
      for (int q = 0; q < 4; ++q) {
        size_t row = rbase + wr * 64 + i * 16 + fg * 4 + q;
        size_t col = cbase + wc * 64 + j * 16 + fr;
        float vv = acc[i][j][q];
        vv = vv > 0.f ? vv : 0.f;
        Cp[row * 512 + col] = f2bf(vv);
      }
}

// Fused layers 2+3: 64 rows x 256 cols (full N), 8 waves (2x4, wave 32x64), BK=32,
// 16 K-steps, all-GLL dbuf. __launch_bounds__(512,4) -> 2 blocks/CU (grid 512 = 2/CU).
__global__ __launch_bounds__(512, 4) void gemm23(
    const u16* __restrict__ m1, const u16* __restrict__ W1b,
    const u16* __restrict__ W2b, float* __restrict__ out)
{
  __shared__ u16 pool[20480];    // A dbuf 2x4KB @0 | B dbuf 2x16KB @8192; reused as m2 [64][264]
  __shared__ u16 W2s[16][264];
  const int t = threadIdx.x, w = t >> 6, lane = t & 63;
  const size_t rbase = (size_t)blockIdx.x * 64;
  const int wr = w >> 2, wc = w & 3, fr = lane & 15, fg = lane >> 4;

  // stage W2 once (16x256 = 512 int4 chunks, 512 threads)
  {
    int r = t >> 5, kc = (t & 31) * 8;
    *(int4*)&W2s[r][kc] = *(const int4*)(W2b + r * 256 + kc);
  }

  int aOff[2], bOff[4];
#pragma unroll
  for (int i = 0; i < 2; ++i) aOff[i] = swz((wr * 32 + i * 16 + fr) * 64 + fg * 16);
#pragma unroll
  for (int j = 0; j < 4; ++j) bOff[j] = swz((wc * 64 + j * 16 + fr) * 64 + fg * 16);

  // A tile 64x32 = 4KB: waves 0-3 issue 1 GLL each
  const u16* aSrc = nullptr; int aDst = 0;
  if (w < 4) {
    int Dl = (w * 64 + lane) * 16;
    int Ul = swz(Dl);
    aSrc = m1 + (rbase + (Ul >> 6)) * 512 + ((Ul & 63) >> 1);
    aDst = (w * 64) * 16;
  }
  // B tile 256x32 = 16KB: 2 GLL per wave
  const u16* bSrc[2]; int bDst[2];
#pragma unroll
  for (int i = 0; i < 2; ++i) {
    int Dl = (w * 128 + i * 64 + lane) * 16;
    int Ul = swz(Dl);
    bSrc[i] = W1b + (Ul >> 6) * 512 + ((Ul & 63) >> 1);
    bDst[i] = 8192 + (w * 128 + i * 64) * 16;   // byte offset into pool (B base = 8192B)
  }

  f32x4 acc[2][4];
#pragma unroll
  for (int i = 0; i < 2; ++i)
#pragma unroll
    for (int j = 0; j < 4; ++j) acc[i][j] = (f32x4){0.f, 0.f, 0.f, 0.f};

  // prologue: tile 0 into buf0
  if (w < 4) GLL16(aSrc, (char*)pool + aDst);
#pragma unroll
  for (int i = 0; i < 2; ++i) GLL16(bSrc[i], (char*)pool + bDst[i]);

  for (int tt = 0; tt < 16; ++tt) {
    const int cur = tt & 1;
    const char* Asc = (const char*)pool + cur * 4096;
    const char* Bsc = (const char*)pool + 8192 + cur * 16384;
    asm volatile("s_waitcnt vmcnt(0)" ::: "memory");
    __syncthreads();

    if (tt < 15) {
      const int k0 = (tt + 1) * 32;
      if (w < 4) GLL16(aSrc + k0, (char*)pool + (cur ^ 1) * 4096 + aDst);
#pragma unroll
      for (int i = 0; i < 2; ++i)
        GLL16(bSrc[i] + k0, (char*)pool + (cur ^ 1) * 16384 + bDst[i]);
    }

    bhalf8 af[2], bfv[4];
#pragma unroll
    for (int i = 0; i < 2; ++i) af[i] = *(const bhalf8*)(Asc + aOff[i]);
#pragma unroll
    for (int j = 0; j < 4; ++j) bfv[j] = *(const bhalf8*)(Bsc + bOff[j]);
#pragma unroll
    for (int i = 0; i < 2; ++i)
#pragma unroll
      for (int j = 0; j < 4; ++j)
        acc[i][j] = __builtin_amdgcn_mfma_f32_16x16x32_bf16(af[i], bfv[j], acc[i][j], 0, 0, 0);
  }

  __syncthreads();                       // everyone done reading staging LDS
  // m2 = relu(acc) -> bf16 into pool as [64][264]
#pragma unroll
  for (int i = 0; i < 2; ++i)
#pragma unroll
    for (int j = 0; j < 4; ++j)
#pragma unroll
      for (int q = 0; q < 4; ++q) {
        int row = wr * 32 + i * 16 + fg * 4 + q;
        int col = wc * 64 + j * 16 + fr;
        float vv = acc[i][j][q];
        vv = vv > 0.f ? vv : 0.f;
        pool[row * 264 + col] = f2bf(vv);
      }
  __syncthreads();

  // layer 3: waves 0-3 handle rows w*16..w*16+15; K=256 (8 ksubs)
  if (w < 4) {
    f32x4 acc3 = (f32x4){0.f, 0.f, 0.f, 0.f};
    const int arow = w * 16 + fr;
#pragma unroll
    for (int ks = 0; ks < 8; ++ks) {
      bhalf8 a = *(const bhalf8*)&pool[arow * 264 + ks * 32 + fg * 8];
      bhalf8 b = *(const bhalf8*)&W2s[fr][ks * 32 + fg * 8];
      acc3 = __builtin_amdgcn_mfma_f32_16x16x32_bf16(a, b, acc3, 0, 0, 0);
    }
    if (fr < 10) {
#pragma unroll
      for (int q = 0; q < 4; ++q) {
        size_t row = rbase + w * 16 + fg * 4 + q;
        float vv = acc3[q];
        out[row * 10 + fr] = vv > 0.f ? vv : 0.f;
      }
    }
  }
}

extern "C" void kernel_launch(void* const* d_in, const int* in_sizes, int n_in,
                              void* d_out, int out_size, void* d_ws, size_t ws_size,
                              hipStream_t stream) {
  const float* x  = (const float*)d_in[0];
  const float* W0 = (const float*)d_in[1];
  const float* W1 = (const float*)d_in[2];
  const float* W2 = (const float*)d_in[3];
  float* out = (float*)d_out;

  char* ws = (char*)d_ws;
  u16* m1  = (u16*)(ws);                    // 32768x512 bf16 = 33554432 B
  u16* W0b = (u16*)(ws + 33554432);         // 512x832 = 851968 B
  u16* W1b = (u16*)(ws + 34406400);         // 256x512 = 262144 B
  u16* W2b = (u16*)(ws + 34668544);         // 16x256  = 8192 B

  cvt_weights<<<dim3((W0E + W1E + W2E + 255) / 256), dim3(256), 0, stream>>>(
      W0, W1, W2, W0b, W1b, W2b);

  // m1 = relu(x @ W0^T): 256 row tiles x 4 col tiles, 4 blocks/CU resident
  gemm1<<<dim3(1024), dim3(256), 0, stream>>>(x, W0b, m1);

  // out = relu(relu(m1 @ W1^T) @ W2^T): fused layers 2+3, 2 blocks/CU
  gemm23<<<dim3(512), dim3(512), 0, stream>>>(m1, W1b, W2b, out);
}